// Round 2
// baseline (242.760 us; speedup 1.0000x reference)
//
#include <hip/hip_runtime.h>

// Dist_Conv2D: out[b,f,h,w] = max_{c,i,j} |W[f, c*9+i*3+j] - x_pad[b,c,h+i,w+j]| + bias[f]
// x: (4,16,64,64) f32, W: (64,144) f32, bias: (64,) f32, out: (4,64,64,64) f32
// replicate pad 1 on each side of H,W.

#define BB 4
#define CC 16
#define HH 64
#define WW 64
#define FF 64
#define FCHUNK 4   // filters per thread: 16 f-chunks -> 262144 threads = 16 waves/CU

__global__ __launch_bounds__(256, 4) void dist_conv2d_kernel(
    const float* __restrict__ x,
    const float* __restrict__ wgt,
    const float* __restrict__ bias,
    float* __restrict__ out) {
    int tid = blockIdx.x * blockDim.x + threadIdx.x;
    // tid = ((fc * BB + b) * HH + h) * WW + w ; lanes vary only in w
    int w  = tid & 63;
    int h  = (tid >> 6) & 63;
    int b  = (tid >> 12) & 3;
    int fc = tid >> 14;          // 0..15
    int f0 = fc * FCHUNK;

    // replicate-pad clamped neighbor indices
    int r0 = h - 1; if (r0 < 0) r0 = 0;
    int r2 = h + 1; if (r2 > HH - 1) r2 = HH - 1;
    int c0 = w - 1; if (c0 < 0) c0 = 0;
    int c2 = w + 1; if (c2 > WW - 1) c2 = WW - 1;
    int row0 = r0 * WW, row1 = h * WW, row2 = r2 * WW;

    const float* xb = x + b * (CC * HH * WW);
    const float* wbase = wgt + f0 * (CC * 9);   // wave-uniform

    float dist[FCHUNK];
#pragma unroll
    for (int i = 0; i < FCHUNK; ++i) dist[i] = 0.0f;

#define LOADP(P, C) do {                                        \
        const float* xc_ = xb + (C) * (HH * WW);                \
        P[0] = xc_[row0 + c0]; P[1] = xc_[row0 + w]; P[2] = xc_[row0 + c2]; \
        P[3] = xc_[row1 + c0]; P[4] = xc_[row1 + w]; P[5] = xc_[row1 + c2]; \
        P[6] = xc_[row2 + c0]; P[7] = xc_[row2 + w]; P[8] = xc_[row2 + c2]; \
    } while (0)

    float pc[9], pn[9];
    LOADP(pc, 0);

#pragma unroll
    for (int c = 0; c < CC; ++c) {
        if (c + 1 < CC) LOADP(pn, c + 1);     // prefetch next channel's patch
#pragma unroll
        for (int fi = 0; fi < FCHUNK; ++fi) {
            const float* wrow = wbase + fi * (CC * 9) + c * 9;  // s_load, uniform
#pragma unroll
            for (int k = 0; k < 9; ++k) {
                float d = pc[k] - wrow[k];
                dist[fi] = fmaxf(dist[fi], fabsf(d));
            }
        }
        // rotate (register-renamed away after full unroll)
#pragma unroll
        for (int k = 0; k < 9; ++k) pc[k] = pn[k];
    }
#undef LOADP

    float* ob = out + ((b * FF + f0) * HH + h) * WW + w;
#pragma unroll
    for (int fi = 0; fi < FCHUNK; ++fi) {
        ob[fi * (HH * WW)] = dist[fi] + bias[f0 + fi];
    }
}

extern "C" void kernel_launch(void* const* d_in, const int* in_sizes, int n_in,
                              void* d_out, int out_size, void* d_ws, size_t ws_size,
                              hipStream_t stream) {
    const float* x    = (const float*)d_in[0];
    const float* wgt  = (const float*)d_in[1];
    const float* bias = (const float*)d_in[2];
    float* out = (float*)d_out;

    const int total = (FF / FCHUNK) * BB * HH * WW;  // 262144 threads
    dist_conv2d_kernel<<<total / 256, 256, 0, stream>>>(x, wgt, bias, out);
}

// Round 3
// 27.551 us; speedup vs baseline: 8.8112x; 8.8112x over previous
//
#include <hip/hip_runtime.h>

// Dist_Conv2D: out[b,f,h,w] = max_{c,i,j} |W[f, c*9+i*3+j] - x_pad[b,c,h+i,w+j]| + bias[f]
// x: (4,16,64,64) f32, W: (64,144) f32, bias: (64,) f32, out: (4,64,64,64) f32
// replicate pad 1 on each side of H,W.
//
// R3: exact R1 structure (proven 26us, no spill), single change: FCHUNK 8->4
// to double TLP (1024 blocks = 16 waves/CU = 4 waves/SIMD).
// NOTE: no min-waves __launch_bounds__ — (256,4) in R2 capped VGPR at 64 and
// caused scratch spill (225MB fetch / 450MB write, VALUBusy 3%).

#define BB 4
#define CC 16
#define HH 64
#define WW 64
#define FF 64
#define FCHUNK 4

__global__ __launch_bounds__(256) void dist_conv2d_kernel(
    const float* __restrict__ x,
    const float* __restrict__ wgt,
    const float* __restrict__ bias,
    float* __restrict__ out) {
    int tid = blockIdx.x * blockDim.x + threadIdx.x;
    // tid = ((fc * BB + b) * HH + h) * WW + w ; lanes vary only in w -> f,b,h wave-uniform
    int w  = tid & 63;
    int h  = (tid >> 6) & 63;
    int b  = (tid >> 12) & 3;
    int fc = tid >> 14;          // 0..15
    int f0 = fc * FCHUNK;

    // replicate-pad clamped neighbor indices
    int r0 = h - 1; if (r0 < 0) r0 = 0;
    int r2 = h + 1; if (r2 > HH - 1) r2 = HH - 1;
    int c0 = w - 1; if (c0 < 0) c0 = 0;
    int c2 = w + 1; if (c2 > WW - 1) c2 = WW - 1;
    int row0 = r0 * WW, row1 = h * WW, row2 = r2 * WW;

    float dist[FCHUNK];
#pragma unroll
    for (int i = 0; i < FCHUNK; ++i) dist[i] = 0.0f;  // |.| >= 0, safe identity

    const float* xb = x + b * (CC * HH * WW);
    for (int c = 0; c < CC; ++c) {
        const float* xc = xb + c * (HH * WW);
        float p[9];
        p[0] = xc[row0 + c0]; p[1] = xc[row0 + w]; p[2] = xc[row0 + c2];
        p[3] = xc[row1 + c0]; p[4] = xc[row1 + w]; p[5] = xc[row1 + c2];
        p[6] = xc[row2 + c0]; p[7] = xc[row2 + w]; p[8] = xc[row2 + c2];
#pragma unroll
        for (int fi = 0; fi < FCHUNK; ++fi) {
            const float* wrow = wgt + (f0 + fi) * (CC * 9) + c * 9;  // wave-uniform -> s_load
#pragma unroll
            for (int k = 0; k < 9; ++k) {
                float d = p[k] - wrow[k];
                dist[fi] = fmaxf(dist[fi], fabsf(d));  // v_max_f32 with |d| modifier
            }
        }
    }

    float* ob = out + ((b * FF + f0) * HH + h) * WW + w;
#pragma unroll
    for (int fi = 0; fi < FCHUNK; ++fi) {
        ob[fi * (HH * WW)] = dist[fi] + bias[f0 + fi];
    }
}

extern "C" void kernel_launch(void* const* d_in, const int* in_sizes, int n_in,
                              void* d_out, int out_size, void* d_ws, size_t ws_size,
                              hipStream_t stream) {
    const float* x    = (const float*)d_in[0];
    const float* wgt  = (const float*)d_in[1];
    const float* bias = (const float*)d_in[2];
    float* out = (float*)d_out;

    const int total = (FF / FCHUNK) * BB * HH * WW;  // 262144 threads, 1024 blocks
    dist_conv2d_kernel<<<total / 256, 256, 0, stream>>>(x, wgt, bias, out);
}

// Round 4
// 15.206 us; speedup vs baseline: 15.9651x; 1.8119x over previous
//
#include <hip/hip_runtime.h>

// Dist_Conv2D: out[b,f,h,w] = max_{c,i,j} |W[f, c*9+i*3+j] - x_pad[b,c,h+i,w+j]| + bias[f]
// x: (4,16,64,64) f32, W: (64,144) f32, bias: (64,) f32, out: (4,64,64,64) f32
// replicate pad 1 on each side of H,W.
//
// R4: make filter/batch indices SGPR-provable (derive from blockIdx.x, NOT from
// the per-thread tid) so weight+bias loads become scalar s_load instead of 576
// broadcast VMEM loads per thread (R1/R3's hidden cost: ~720 VMEM instrs + addr
// math per thread -> VMEM-issue bound at 27us).

#define BB 4
#define CC 16
#define HH 64
#define WW 64
#define FF 64
#define FCHUNK 4

__global__ __launch_bounds__(256) void dist_conv2d_kernel(
    const float* __restrict__ x,
    const float* __restrict__ wgt,
    const float* __restrict__ bias,
    float* __restrict__ out) {
    // block covers 256 threads = (h_lo(2) | w(6)); blockIdx bits: fc(4)|b(2)|h_hi(4)
    int w  = threadIdx.x & 63;
    int h  = ((blockIdx.x & 15) << 2) | (threadIdx.x >> 6);
    int b  = (blockIdx.x >> 4) & 3;        // SGPR
    int fc = blockIdx.x >> 6;              // SGPR, 0..15
    int f0 = fc * FCHUNK;                  // SGPR

    // replicate-pad clamped neighbor indices
    int r0 = h - 1; if (r0 < 0) r0 = 0;
    int r2 = h + 1; if (r2 > HH - 1) r2 = HH - 1;
    int c0 = w - 1; if (c0 < 0) c0 = 0;
    int c2 = w + 1; if (c2 > WW - 1) c2 = WW - 1;
    int row0 = r0 * WW, row1 = h * WW, row2 = r2 * WW;

    float dist[FCHUNK];
#pragma unroll
    for (int i = 0; i < FCHUNK; ++i) dist[i] = 0.0f;

    const float* xb    = x + b * (CC * HH * WW);     // SGPR base + 0
    const float* wbase = wgt + f0 * (CC * 9);        // SGPR base -> s_load

#pragma unroll 4
    for (int c = 0; c < CC; ++c) {
        const float* xc = xb + c * (HH * WW);
        float p[9];
        p[0] = xc[row0 + c0]; p[1] = xc[row0 + w]; p[2] = xc[row0 + c2];
        p[3] = xc[row1 + c0]; p[4] = xc[row1 + w]; p[5] = xc[row1 + c2];
        p[6] = xc[row2 + c0]; p[7] = xc[row2 + w]; p[8] = xc[row2 + c2];
#pragma unroll
        for (int fi = 0; fi < FCHUNK; ++fi) {
            const float* wrow = wbase + fi * (CC * 9) + c * 9;   // uniform -> s_load
#pragma unroll
            for (int k = 0; k < 9; ++k) {
                float d = p[k] - wrow[k];
                dist[fi] = fmaxf(dist[fi], fabsf(d));
            }
        }
    }

    float* ob = out + ((b * FF + f0) * HH + h) * WW + w;
#pragma unroll
    for (int fi = 0; fi < FCHUNK; ++fi) {
        ob[fi * (HH * WW)] = dist[fi] + bias[f0 + fi];   // bias: s_load
    }
}

extern "C" void kernel_launch(void* const* d_in, const int* in_sizes, int n_in,
                              void* d_out, int out_size, void* d_ws, size_t ws_size,
                              hipStream_t stream) {
    const float* x    = (const float*)d_in[0];
    const float* wgt  = (const float*)d_in[1];
    const float* bias = (const float*)d_in[2];
    float* out = (float*)d_out;

    const int total = (FF / FCHUNK) * BB * HH * WW;  // 262144 threads, 1024 blocks
    dist_conv2d_kernel<<<total / 256, 256, 0, stream>>>(x, wgt, bias, out);
}

// Round 5
// 13.420 us; speedup vs baseline: 18.0889x; 1.1330x over previous
//
#include <hip/hip_runtime.h>

// Dist_Conv2D: out[b,f,h,w] = max_{c,i,j} |W[f, c*9+i*3+j] - x_pad[b,c,h+i,w+j]| + bias[f]
// x: (4,16,64,64) f32, W: (64,144) f32, bias: (64,) f32, out: (4,64,64,64) f32
// replicate pad 1 on each side of H,W.
//
// R5: wave-shuffle stencil sharing. w == lane spans the full row (W=64==wave64),
// so left/right patch columns come from __shfl_up/__shfl_down(v,1), whose
// out-of-range behavior (lane keeps own value) IS replicate padding at w=0/63.
// Per-channel x traffic: 9 loads -> 3 loads + 6 shuffles. (R4: weight loads
// scalar via SGPR-provable f0 — keep. R2 lesson: no min-waves bound.)

#define BB 4
#define CC 16
#define HH 64
#define WW 64
#define FF 64
#define FCHUNK 4

__global__ __launch_bounds__(256) void dist_conv2d_kernel(
    const float* __restrict__ x,
    const float* __restrict__ wgt,
    const float* __restrict__ bias,
    float* __restrict__ out) {
    // block = 256 threads = (h_lo(2) | w(6)); blockIdx bits: fc(4)|b(2)|h_hi(4)
    int w  = threadIdx.x & 63;             // lane id
    int h  = ((blockIdx.x & 15) << 2) | (threadIdx.x >> 6);
    int b  = (blockIdx.x >> 4) & 3;        // SGPR
    int fc = blockIdx.x >> 6;              // SGPR, 0..15
    int f0 = fc * FCHUNK;                  // SGPR

    // replicate-pad clamped row indices (columns handled by shuffle semantics)
    int r0 = h - 1; if (r0 < 0) r0 = 0;
    int r2 = h + 1; if (r2 > HH - 1) r2 = HH - 1;
    int row0 = r0 * WW + w, row1 = h * WW + w, row2 = r2 * WW + w;

    float dist[FCHUNK];
#pragma unroll
    for (int i = 0; i < FCHUNK; ++i) dist[i] = 0.0f;

    const float* xb    = x + b * (CC * HH * WW);
    const float* wbase = wgt + f0 * (CC * 9);        // SGPR base -> s_load

#pragma unroll 4
    for (int c = 0; c < CC; ++c) {
        const float* xc = xb + c * (HH * WW);
        float v0 = xc[row0], v1 = xc[row1], v2 = xc[row2];   // 3 loads/channel
        float p[9];
        p[0] = __shfl_up(v0, 1);  p[1] = v0;  p[2] = __shfl_down(v0, 1);
        p[3] = __shfl_up(v1, 1);  p[4] = v1;  p[5] = __shfl_down(v1, 1);
        p[6] = __shfl_up(v2, 1);  p[7] = v2;  p[8] = __shfl_down(v2, 1);
#pragma unroll
        for (int fi = 0; fi < FCHUNK; ++fi) {
            const float* wrow = wbase + fi * (CC * 9) + c * 9;   // uniform -> s_load
#pragma unroll
            for (int k = 0; k < 9; ++k) {
                float d = p[k] - wrow[k];
                dist[fi] = fmaxf(dist[fi], fabsf(d));
            }
        }
    }

    float* ob = out + ((b * FF + f0) * HH + h) * WW + w;
#pragma unroll
    for (int fi = 0; fi < FCHUNK; ++fi) {
        ob[fi * (HH * WW)] = dist[fi] + bias[f0 + fi];   // bias: s_load
    }
}

extern "C" void kernel_launch(void* const* d_in, const int* in_sizes, int n_in,
                              void* d_out, int out_size, void* d_ws, size_t ws_size,
                              hipStream_t stream) {
    const float* x    = (const float*)d_in[0];
    const float* wgt  = (const float*)d_in[1];
    const float* bias = (const float*)d_in[2];
    float* out = (float*)d_out;

    const int total = (FF / FCHUNK) * BB * HH * WW;  // 262144 threads, 1024 blocks
    dist_conv2d_kernel<<<total / 256, 256, 0, stream>>>(x, wgt, bias, out);
}